// Round 2
// baseline (1702.022 us; speedup 1.0000x reference)
//
#include <hip/hip_runtime.h>
#include <stdint.h>

#define CCH 64
#define KK 27
#define SHIFT0 31
#define SHIFT1 31
#define PRELU_SHIFT 25

// exact signed per-byte dot product of two packed-int8 dwords into int32
__device__ __forceinline__ int sdot4i8(int a, int b, int c) {
    c += ((a << 24) >> 24) * ((b << 24) >> 24);
    c += ((a << 16) >> 24) * ((b << 16) >> 24);
    c += ((a <<  8) >> 24) * ((b <<  8) >> 24);
    c += ( a        >> 24) * ( b        >> 24);
    return c;
}

__device__ __forceinline__ long long clip127(long long v) {
    return v > 127 ? 127 : (v < -127 ? -127 : v);
}

// repack int8-valued int32 array -> packed int8
__global__ void k_pack8(const int* __restrict__ src, int8_t* __restrict__ dst, int n) {
    int i = blockIdx.x * blockDim.x + threadIdx.x;
    if (i < n) dst[i] = (int8_t)src[i];
}

// q0 = clip((x32 * mul0) >> 31) as packed int8 (4 per dword)
__global__ void k_requant0(const int* __restrict__ x,
                           const int* __restrict__ mulp,
                           int* __restrict__ q0,
                           int total4) {
    const long long mul = (long long)(*mulp);
    int i = blockIdx.x * blockDim.x + threadIdx.x;
    const int stride = gridDim.x * blockDim.x;
    for (; i < total4; i += stride) {
        int4 v = ((const int4*)x)[i];
        long long t;
        int r = 0;
        t = ((long long)v.x * mul) >> SHIFT0; t = clip127(t); r |= (int)(t & 0xff);
        t = ((long long)v.y * mul) >> SHIFT0; t = clip127(t); r |= (int)(t & 0xff) << 8;
        t = ((long long)v.z * mul) >> SHIFT0; t = clip127(t); r |= (int)(t & 0xff) << 16;
        t = ((long long)v.w * mul) >> SHIFT0; t = clip127(t); r |= (int)(t & 0xff) << 24;
        q0[i] = r;
    }
}

// One wave (64 lanes) per voxel; 4 voxels per 256-thread block.
// LAYER==1: epilogue = PReLU + per-channel requant -> int8 q1out
// LAYER==2: epilogue = residual add with x32 -> int32 out
template <int LAYER>
__global__ void __launch_bounds__(256)
k_conv(const int8_t* __restrict__ fin,        // [nvox*64] int8 activations (packed)
       const int* __restrict__ in_idx,        // [nvox*27] int32
       const int* __restrict__ mask,          // [nvox*27] int32 (0/1)
       const int8_t* __restrict__ w,          // [27*64*64] packed int8 (k, out, in)
       const int* __restrict__ bias,          // [64]
       const int* __restrict__ comp,          // [27*64]
       const int* __restrict__ mul1,          // [64]   (layer 1)
       const int* __restrict__ slopep,        // scalar (layer 1)
       const int* __restrict__ x32,           // [nvox*64] residual (layer 2)
       int8_t* __restrict__ q1out,            // layer-1 output
       int* __restrict__ out,                 // layer-2 output
       int nvox) {
    __shared__ int s_act[4][KK * 16];   // gathered neighborhood, 27 rows x 64B
    __shared__ int s_idx[4][KK];
    __shared__ int s_msk[4][KK];

    const int wave = threadIdx.x >> 6;
    const int lane = threadIdx.x & 63;
    const int n = blockIdx.x * 4 + wave;
    const bool valid = n < nvox;

    if (valid && lane < KK) {
        s_idx[wave][lane] = in_idx[n * KK + lane];
        s_msk[wave][lane] = mask[n * KK + lane];
    }
    __syncthreads();

    if (valid) {
        const int* fin32 = (const int*)fin;
        for (int t = lane; t < KK * 16; t += 64) {
            const int r = t >> 4, d = t & 15;
            int v = 0;
            if (s_msk[wave][r]) v = fin32[s_idx[wave][r] * 16 + d];
            s_act[wave][t] = v;
        }
    }
    __syncthreads();
    if (!valid) return;

    const int o = lane;
    int acc = bias[o];
    const int* actw = s_act[wave];
    for (int k = 0; k < KK; ++k) {
        acc += s_msk[wave][k] ? comp[k * CCH + o] : 0;
        const int4* wp = (const int4*)(w + ((size_t)(k * CCH + o)) * CCH);
        const int4* ap = (const int4*)(actw + k * 16);
#pragma unroll
        for (int d = 0; d < 4; ++d) {
            int4 wv = wp[d];
            int4 av = ap[d];
            acc = sdot4i8(av.x, wv.x, acc);
            acc = sdot4i8(av.y, wv.y, acc);
            acc = sdot4i8(av.z, wv.z, acc);
            acc = sdot4i8(av.w, wv.w, acc);
        }
    }

    if (LAYER == 1) {
        long long p = acc;
        if (p < 0) p = (p * (long long)(*slopep)) >> PRELU_SHIFT;
        long long v = (p * (long long)mul1[o]) >> SHIFT1;
        v = clip127(v);
        q1out[(size_t)n * CCH + o] = (int8_t)v;
    } else {
        out[(size_t)n * CCH + o] = acc + x32[(size_t)n * CCH + o];
    }
}

extern "C" void kernel_launch(void* const* d_in, const int* in_sizes, int n_in,
                              void* d_out, int out_size, void* d_ws, size_t ws_size,
                              hipStream_t stream) {
    // ALL integer inputs arrive as int32 on device, regardless of reference dtype.
    const int* x32    = (const int*)d_in[0];
    const int* in_idx = (const int*)d_in[1];
    const int* mask   = (const int*)d_in[2];
    const int* w1_32  = (const int*)d_in[3];
    const int* b1     = (const int*)d_in[4];
    const int* comp1  = (const int*)d_in[5];
    const int* w2_32  = (const int*)d_in[6];
    const int* b2     = (const int*)d_in[7];
    const int* comp2  = (const int*)d_in[8];
    const int* mul0   = (const int*)d_in[9];
    const int* mul1   = (const int*)d_in[10];
    const int* slope  = (const int*)d_in[11];

    const int nvox = in_sizes[0] / CCH;                 // 100000
    const int wn = KK * CCH * CCH;                      // 110592 weight elements
    const size_t fbytes = (size_t)nvox * CCH;           // 6.4 MB per int8 feature map
    const size_t falign = (fbytes + 255) & ~(size_t)255;
    const size_t walign = ((size_t)wn + 255) & ~(size_t)255;

    int8_t* q0;
    int8_t* q1;
    int8_t* w1p;
    int8_t* w2p;
    if (ws_size >= 2 * falign + 2 * walign) {
        q0  = (int8_t*)d_ws;
        q1  = q0 + falign;
        w1p = q1 + falign;
        w2p = w1p + walign;
    } else {
        // stage q0 in d_out's bytes (dead after conv1; conv2 rewrites d_out fully)
        q0  = (int8_t*)d_out;
        q1  = (int8_t*)d_ws;
        w1p = q1 + falign;
        w2p = w1p + walign;
    }

    const int pblocks = (wn + 255) / 256;
    k_pack8<<<pblocks, 256, 0, stream>>>(w1_32, w1p, wn);
    k_pack8<<<pblocks, 256, 0, stream>>>(w2_32, w2p, wn);

    {
        const int total4 = (nvox * CCH) / 4;
        int blocks = (total4 + 255) / 256;
        if (blocks > 4096) blocks = 4096;
        k_requant0<<<blocks, 256, 0, stream>>>(x32, mul0, (int*)q0, total4);
    }

    const int cblocks = (nvox + 3) / 4;
    k_conv<1><<<cblocks, 256, 0, stream>>>(q0, in_idx, mask, w1p, b1, comp1,
                                           mul1, slope, nullptr, q1, nullptr, nvox);
    k_conv<2><<<cblocks, 256, 0, stream>>>(q1, in_idx, mask, w2p, b2, comp2,
                                           nullptr, nullptr, x32, nullptr,
                                           (int*)d_out, nvox);
}

// Round 3
// 208.810 us; speedup vs baseline: 8.1510x; 8.1510x over previous
//
#include <hip/hip_runtime.h>
#include <stdint.h>

#define CCH 64
#define KK 27
#define SHIFT0 31
#define SHIFT1 31
#define PRELU_SHIFT 25

typedef int v4i __attribute__((ext_vector_type(4)));

__device__ __forceinline__ long long clip127(long long v) {
    return v > 127 ? 127 : (v < -127 ? -127 : v);
}

// repack int8-valued int32 array -> packed int8 (weights arrive as int32 on device)
__global__ void k_pack8(const int* __restrict__ src, int8_t* __restrict__ dst, int n) {
    int i = blockIdx.x * blockDim.x + threadIdx.x;
    if (i < n) dst[i] = (int8_t)src[i];
}

// q0 = clip((x32 * mul0) >> 31) as packed int8 (4 per dword)
__global__ void k_requant0(const int* __restrict__ x,
                           const int* __restrict__ mulp,
                           int* __restrict__ q0,
                           int total4) {
    const long long mul = (long long)(*mulp);
    int i = blockIdx.x * blockDim.x + threadIdx.x;
    const int stride = gridDim.x * blockDim.x;
    for (; i < total4; i += stride) {
        int4 v = ((const int4*)x)[i];
        long long t;
        int r = 0;
        t = ((long long)v.x * mul) >> SHIFT0; t = clip127(t); r |= (int)(t & 0xff);
        t = ((long long)v.y * mul) >> SHIFT0; t = clip127(t); r |= (int)(t & 0xff) << 8;
        t = ((long long)v.z * mul) >> SHIFT0; t = clip127(t); r |= (int)(t & 0xff) << 16;
        t = ((long long)v.w * mul) >> SHIFT0; t = clip127(t); r |= (int)(t & 0xff) << 24;
        q0[i] = r;
    }
}

// MFMA conv: 256 threads = 4 waves; one 16-voxel tile per grid-stride iteration.
// Wave w computes output channels [w*16, w*16+16) for all 16 voxels via
// 27 x mfma_i32_16x16x64_i8 (one per kernel offset, K=64 input channels).
// A (16x64, LDS, padded stride 436 dwords): lane l -> row=l&15, k=(l>>4)*16+j
// B (64x16, registers):                     lane l -> k=(l>>4)*16+j, col=l&15
// D (16x16):                                lane l -> row=(l>>4)*4+r, col=l&15
template <int LAYER>
__global__ void __launch_bounds__(256)
k_conv_mfma(const int8_t* __restrict__ fin,   // [nvox*64] int8 activations
            const int* __restrict__ in_idx,   // [nvox*27]
            const int* __restrict__ mask,     // [nvox*27] (0/1)
            const int8_t* __restrict__ w8,    // [27*64*64] packed int8 (k, out, in)
            const int* __restrict__ bias,     // [64]
            const int* __restrict__ comp,     // [27*64]
            const int* __restrict__ mul1,     // [64]   (layer 1)
            const int* __restrict__ slopep,   // scalar (layer 1)
            const int* __restrict__ x32,      // [nvox*64] residual (layer 2)
            int8_t* __restrict__ q1out,       // layer-1 output
            int* __restrict__ out,            // layer-2 output
            int nvox, int ntiles) {
    __shared__ int s_act[16 * 436];   // 16 voxel rows x 1744B (27*64 data + 16B pad)
    __shared__ int s_idx[16 * KK];
    __shared__ int s_msk[16 * KK];
    __shared__ int s_mbits[16];

    const int tid  = threadIdx.x;
    const int lane = tid & 63;
    const int wv   = tid >> 6;            // output-channel tile 0..3
    const int col  = wv * 16 + (lane & 15);
    const int srow = lane >> 4;           // K sub-block 0..3
    const int arow = lane & 15;           // A-fragment voxel row

    // --- per-block preloads (reused across grid-stride tiles) ---
    v4i wreg[KK];
#pragma unroll
    for (int k = 0; k < KK; ++k)
        wreg[k] = *(const v4i*)(w8 + ((size_t)(k * CCH + col)) * CCH + srow * 16);

    int comp_r[KK];
#pragma unroll
    for (int k = 0; k < KK; ++k) comp_r[k] = comp[k * CCH + col];

    const int bias_r = bias[col];
    const int mul_r = (LAYER == 1) ? mul1[col] : 0;
    const long long slope = (LAYER == 1) ? (long long)(*slopep) : 0;

    for (int tile = blockIdx.x; tile < ntiles; tile += gridDim.x) {
        const int nb = tile * 16;

        // stage neighbor indices + masks
        for (int t = tid; t < 16 * KK; t += 256) {
            const int v = t / KK;
            const int k = t - v * KK;
            const int n = nb + v;
            int ix = 0, mk = 0;
            if (n < nvox) {
                ix = in_idx[(size_t)n * KK + k];
                mk = mask[(size_t)n * KK + k];
            }
            s_idx[t] = ix;
            s_msk[t] = mk;
        }
        __syncthreads();

        // pack mask bits per voxel (for epilogue comp term)
        if (tid < 16) {
            int mb = 0;
#pragma unroll
            for (int k = 0; k < KK; ++k) mb |= (s_msk[tid * KK + k] != 0) << k;
            s_mbits[tid] = mb;
        }

        // gather masked activation rows into LDS: (v,k,seg) -> 16B each
        for (int t = tid; t < 16 * KK * 4; t += 256) {
            const int v   = t / (KK * 4);
            const int rem = t - v * (KK * 4);
            const int k   = rem >> 2;
            const int seg = rem & 3;
            v4i val = {0, 0, 0, 0};
            if (s_msk[v * KK + k])
                val = *(const v4i*)(fin + (size_t)s_idx[v * KK + k] * CCH + seg * 16);
            *(v4i*)(&s_act[v * 436 + k * 16 + seg * 4]) = val;
        }
        __syncthreads();

        // K-loop: 27 MFMAs accumulating into one 16x16 tile
        v4i acc = {0, 0, 0, 0};
#pragma unroll
        for (int k = 0; k < KK; ++k) {
            v4i a = *(const v4i*)(&s_act[arow * 436 + k * 16 + srow * 4]);
            acc = __builtin_amdgcn_mfma_i32_16x16x64_i8(a, wreg[k], acc, 0, 0, 0);
        }

        // epilogue: + bias + mask.comp, then PReLU/requant (L1) or residual (L2)
        const int vbase = srow * 4;
#pragma unroll
        for (int r = 0; r < 4; ++r) {
            const int n = nb + vbase + r;
            if (n < nvox) {
                int val = acc[r] + bias_r;
                const int mb = s_mbits[vbase + r];
#pragma unroll
                for (int k = 0; k < KK; ++k)
                    val += ((mb >> k) & 1) ? comp_r[k] : 0;
                if (LAYER == 1) {
                    long long p = val;
                    if (val < 0) p = (p * slope) >> PRELU_SHIFT;
                    long long q = (p * (long long)mul_r) >> SHIFT1;
                    q = clip127(q);
                    q1out[(size_t)n * CCH + col] = (int8_t)q;
                } else {
                    out[(size_t)n * CCH + col] = val + x32[(size_t)n * CCH + col];
                }
            }
        }
        __syncthreads();   // protect s_act/s_idx before next tile's staging
    }
}

extern "C" void kernel_launch(void* const* d_in, const int* in_sizes, int n_in,
                              void* d_out, int out_size, void* d_ws, size_t ws_size,
                              hipStream_t stream) {
    // ALL integer inputs arrive as int32 on device, regardless of reference dtype.
    const int* x32    = (const int*)d_in[0];
    const int* in_idx = (const int*)d_in[1];
    const int* mask   = (const int*)d_in[2];
    const int* w1_32  = (const int*)d_in[3];
    const int* b1     = (const int*)d_in[4];
    const int* comp1  = (const int*)d_in[5];
    const int* w2_32  = (const int*)d_in[6];
    const int* b2     = (const int*)d_in[7];
    const int* comp2  = (const int*)d_in[8];
    const int* mul0   = (const int*)d_in[9];
    const int* mul1   = (const int*)d_in[10];
    const int* slope  = (const int*)d_in[11];

    const int nvox = in_sizes[0] / CCH;                 // 100000
    const int wn = KK * CCH * CCH;                      // 110592 weight elements
    const size_t fbytes = (size_t)nvox * CCH;           // 6.4 MB per int8 feature map
    const size_t falign = (fbytes + 255) & ~(size_t)255;
    const size_t walign = ((size_t)wn + 255) & ~(size_t)255;

    int8_t* q0;
    int8_t* q1;
    int8_t* w1p;
    int8_t* w2p;
    if (ws_size >= 2 * falign + 2 * walign) {
        q0  = (int8_t*)d_ws;
        q1  = q0 + falign;
        w1p = q1 + falign;
        w2p = w1p + walign;
    } else {
        // stage q0 in d_out's bytes (dead after conv1; conv2 rewrites d_out fully)
        q0  = (int8_t*)d_out;
        q1  = (int8_t*)d_ws;
        w1p = q1 + falign;
        w2p = w1p + walign;
    }

    const int pblocks = (wn + 255) / 256;
    k_pack8<<<pblocks, 256, 0, stream>>>(w1_32, w1p, wn);
    k_pack8<<<pblocks, 256, 0, stream>>>(w2_32, w2p, wn);

    {
        const int total4 = (nvox * CCH) / 4;
        int blocks = (total4 + 255) / 256;
        if (blocks > 4096) blocks = 4096;
        k_requant0<<<blocks, 256, 0, stream>>>(x32, mul0, (int*)q0, total4);
    }

    const int ntiles = (nvox + 15) / 16;                // 6250
    int cblocks = (ntiles + 7) / 8;                     // ~8 tiles per block
    if (cblocks > ntiles) cblocks = ntiles;
    k_conv_mfma<1><<<cblocks, 256, 0, stream>>>(q0, in_idx, mask, w1p, b1, comp1,
                                                mul1, slope, nullptr, q1, nullptr,
                                                nvox, ntiles);
    k_conv_mfma<2><<<cblocks, 256, 0, stream>>>(q1, in_idx, mask, w2p, b2, comp2,
                                                nullptr, nullptr, x32, nullptr,
                                                (int*)d_out, nvox, ntiles);
}